// Round 1
// 526.825 us; speedup vs baseline: 1.1952x; 1.1952x over previous
//
#include <hip/hip_runtime.h>
#include <stdint.h>
#include <stddef.h>

#define B_N   2048
#define T_SEQ 200
#define H_DIM 128

typedef __attribute__((ext_vector_type(8))) short short8;
typedef __attribute__((ext_vector_type(4))) float floatx4;

// ws layout (bytes) — total 1,411,072 <= 1,638,400 proven safe in R1
#define OFF_ATT 0u         // ushort[T][B]        819200  (transposed: [t][b])
#define OFF_C   819200u    // float [B][64]       524288
#define OFF_U1  1343488u   // float [128][64]      32768
#define OFF_FR  1376256u   // short8[4][8][64]     32768
#define OFF_W1F 1409024u   // short8[2][64]         2048

__device__ __forceinline__ unsigned rnd_bf(float f) {
  union { float f; unsigned u; } v; v.f = f;
  return v.u + 0x7FFFu + ((v.u >> 16) & 1u);
}
__device__ __forceinline__ unsigned short f2bf(float f) {
  return (unsigned short)(rnd_bf(f) >> 16);
}
// pack two floats -> dword of 2 bf16 (lo in low16) via v_perm_b32
__device__ __forceinline__ unsigned pack2bf(float lo, float hi) {
  return __builtin_amdgcn_perm(rnd_bf(hi), rnd_bf(lo), 0x07060302u);
}
__device__ __forceinline__ float bf2f(unsigned short u) {
  union { unsigned u; float f; } v; v.u = ((unsigned)u) << 16; return v.f;
}

#define LOG2E 1.4426950408889634f
// fast sigmoid/tanh: v_rcp_f32 instead of full-precision divide sequence
// (rel err ~2^-22, far below the bf16 state rounding; saves ~7 VALU each)
__device__ __forceinline__ float fsig(float x) {
  return __builtin_amdgcn_rcpf(1.0f + __builtin_amdgcn_exp2f(-LOG2E * x));
}
__device__ __forceinline__ float ftanh(float x) {
  return fmaf(2.0f, __builtin_amdgcn_rcpf(1.0f + __builtin_amdgcn_exp2f(-2.0f * LOG2E * x)), -1.0f);
}

__device__ __forceinline__ floatx4 mfma16(short8 a, short8 b, floatx4 c) {
  return __builtin_amdgcn_mfma_f32_16x16x32_bf16(a, b, c, 0, 0, 0);
}
__device__ __forceinline__ short8 pack8(const float* p) {
  short8 r;
#pragma unroll
  for (int j = 0; j < 8; ++j) r[j] = (short)f2bf(p[j]);
  return r;
}

// ---------------------------------------------------------------------------
// prep: fold W0 into u1 (fp32, for c-GEMM) and bf16 MFMA B-fragments for
// layer0 (u2|u3) and layer1 (W1^T). Grid-strided over 8 blocks.
// ---------------------------------------------------------------------------
__global__ __launch_bounds__(256) void prep_kernel(
    const float* __restrict__ W0, const float* __restrict__ W1,
    float* __restrict__ u1_ws, short8* __restrict__ fr_ws,
    short8* __restrict__ w1f_ws)
{
  const int gid = blockIdx.x * 256 + threadIdx.x;
  const int gs  = gridDim.x * 256;
  for (int i = gid; i < 128 * 64; i += gs) {
    int k = i >> 6, o = i & 63;
    u1_ws[i] = W0[o * 512 + k] + W0[o * 512 + 256 + k];
  }
  for (int f = gid; f < 4 * 8 * 64; f += gs) {
    int ln = f & 63, kc = (f >> 6) & 7, tt = f >> 9;
    int o = tt * 16 + (ln & 15);
    int k0 = kc * 32 + ((ln >> 4) * 8);
    short8 v;
#pragma unroll
    for (int j = 0; j < 8; ++j) {
      int ks = k0 + j;
      float x = (ks < 128) ? (W0[o * 512 + 128 + ks] - W0[o * 512 + 256 + ks])
                           : W0[o * 512 + 384 + (ks - 128)];
      v[j] = (short)f2bf(x);
    }
    fr_ws[f] = v;
  }
  for (int f = gid; f < 2 * 64; f += gs) {
    int ln = f & 63, kc = f >> 6;
    int n = ln & 15, k0 = kc * 32 + ((ln >> 4) * 8);
    short8 v;
#pragma unroll
    for (int j = 0; j < 8; ++j) v[j] = (short)f2bf(W1[n * 64 + k0 + j]);
    w1f_ws[f] = v;
  }
}

// ---------------------------------------------------------------------------
// c_kernel: c[b][o] = b0[o] + sum_k q[b][k] * u1[k][o].  16 b per block.
// ---------------------------------------------------------------------------
__global__ __launch_bounds__(256) void c_kernel(
    const float* __restrict__ query, const float* __restrict__ u1_ws,
    const float* __restrict__ b0, float* __restrict__ c_ws)
{
  const int blk = blockIdx.x, tid = threadIdx.x;
  __shared__ float qs[16 * 128];
  for (int i = tid; i < 512; i += 256)
    *(float4*)&qs[i * 4] = *(const float4*)(query + (size_t)blk * 2048 + i * 4);
  __syncthreads();
  const int o = tid & 63, bb = tid >> 6;
  float a0 = b0[o], a1 = a0, a2 = a0, a3 = a0;
  const float* qr = qs + bb * 512;
#pragma unroll 4
  for (int k = 0; k < 128; ++k) {
    float w = u1_ws[k * 64 + o];
    a0 = fmaf(qr[k], w, a0);
    a1 = fmaf(qr[128 + k], w, a1);
    a2 = fmaf(qr[256 + k], w, a2);
    a3 = fmaf(qr[384 + k], w, a3);
  }
  const int b = blk * 16 + bb * 4;
  c_ws[(b + 0) * 64 + o] = a0;
  c_ws[(b + 1) * 64 + o] = a1;
  c_ws[(b + 2) * 64 + o] = a2;
  c_ws[(b + 3) * 64 + o] = a3;
}

// ---------------------------------------------------------------------------
// att: layer0 bf16 MFMA (frags from ws), layer1 bf16 MFMA, layer2 tiny dot.
// Output bf16 scores, TRANSPOSED layout attb[t][b] so the scan's staging
// load is coalesced.
// ---------------------------------------------------------------------------
__global__ __launch_bounds__(256) void att_kernel(
    const float* __restrict__ query, const float* __restrict__ keys,
    const float* __restrict__ c_ws, const short8* __restrict__ fr_ws,
    const short8* __restrict__ w1f_ws, const float* __restrict__ b1,
    const float* __restrict__ Wd, const float* __restrict__ bd,
    const int* __restrict__ klen, unsigned short* __restrict__ attb)
{
  const int b   = blockIdx.y;
  const int tt0 = blockIdx.x * 64;
  const int tid = threadIdx.x;
  const int lane = tid & 63, wv = tid >> 6;
  const int kb = (lane >> 4) * 8;

  __shared__ float qs[H_DIM];
  __shared__ __align__(16) unsigned short A[64][264];  // [t][k] bf16, K=256
  __shared__ __align__(16) unsigned short a0b[64][72]; // layer0 activations bf16
  __shared__ float a1s[64][20];

  const int len = klen[b];
  if (tt0 >= len) {
    for (int t2 = tid; t2 < 64; t2 += 256) {
      int tg = tt0 + t2;
      if (tg < T_SEQ) attb[(size_t)tg * B_N + b] = 0;
    }
    return;
  }

  if (tid < H_DIM) qs[tid] = query[(size_t)b * H_DIM + tid];
  __syncthreads();

  {  // stage A = [k | q*k] bf16
    int tl = tid >> 2, q4 = tid & 3;
    int tg = tt0 + tl;
    bool v = (tg < T_SEQ);
    const float* krow = keys + ((size_t)b * T_SEQ + (v ? tg : 0)) * H_DIM + q4 * 32;
#pragma unroll
    for (int i = 0; i < 32; i += 4) {
      float4 kv = v ? *(const float4*)(krow + i) : make_float4(0.f, 0.f, 0.f, 0.f);
      int col = q4 * 32 + i;
      *(unsigned*)&A[tl][col]     = pack2bf(kv.x, kv.y);
      *(unsigned*)&A[tl][col + 2] = pack2bf(kv.z, kv.w);
      *(unsigned*)&A[tl][128 + col]     = pack2bf(kv.x * qs[col + 0], kv.y * qs[col + 1]);
      *(unsigned*)&A[tl][128 + col + 2] = pack2bf(kv.z * qs[col + 2], kv.w * qs[col + 3]);
    }
  }
  // B-fragments for this wave's o-tile (prebuilt in ws)
  short8 bf[8];
  {
    const short8* frp = fr_ws + (size_t)wv * 8 * 64;
#pragma unroll
    for (int kc = 0; kc < 8; ++kc) bf[kc] = frp[kc * 64 + lane];
  }
  const float co = c_ws[(size_t)b * 64 + wv * 16 + (lane & 15)];
  __syncthreads();

  // layer0 MFMA
#pragma unroll
  for (int tt = 0; tt < 4; ++tt) {
    floatx4 acc = {co, co, co, co};
    int row = tt * 16 + (lane & 15);
#pragma unroll
    for (int kc = 0; kc < 8; ++kc)
      acc = mfma16(*(const short8*)&A[row][kc * 32 + kb], bf[kc], acc);
#pragma unroll
    for (int r = 0; r < 4; ++r)
      a0b[tt * 16 + (lane >> 4) * 4 + r][wv * 16 + (lane & 15)] = f2bf(fsig(acc[r]));
  }
  __syncthreads();

  // layer1 MFMA: wave wv owns t-rows wv*16..+15, 16 outputs
  {
    short8 w1f0 = w1f_ws[lane], w1f1 = w1f_ws[64 + lane];
    float b1v = b1[lane & 15];
    floatx4 acc1 = {b1v, b1v, b1v, b1v};
    int r2 = wv * 16 + (lane & 15);
    acc1 = mfma16(*(const short8*)&a0b[r2][kb],      w1f0, acc1);
    acc1 = mfma16(*(const short8*)&a0b[r2][32 + kb], w1f1, acc1);
#pragma unroll
    for (int r = 0; r < 4; ++r)
      a1s[wv * 16 + (lane >> 4) * 4 + r][lane & 15] = fsig(acc1[r]);
  }
  __syncthreads();

  if (tid < 64) {
    int tg = tt0 + tid;
    if (tg < T_SEQ) {
      float s = bd[0];
#pragma unroll
      for (int i = 0; i < 16; ++i) s += a1s[tid][i] * Wd[i];
      attb[(size_t)tg * B_N + b] = (tg < len) ? f2bf(s) : (unsigned short)0;
    }
  }
}

// ---------------------------------------------------------------------------
// AUGRU scan v2: 128 blocks x 16 rows x 512 thr, ONE lgkm-only barrier/step.
// Changes vs v1:
//  - k fragments register-prefetched one step ahead from LDS (kbf is written
//    a step early, so the read is pre-barrier-safe). The 12 k-side MFMAs of
//    step t issue immediately after the barrier with NO LDS wait, covering
//    the h ds_read latency.
//  - r/z accumulators split into independent h/k chains (dep chain 8 -> 4).
//  - rcp-based sigmoid/tanh (no precise-divide sequences).
//  - att values fetched 4-at-a-time via one ds_read_b128.
//  - 2-step unroll: all LDS buffer indices compile-time constants, no
//    register copies for the ak/kv double buffers.
// ---------------------------------------------------------------------------
__global__ __launch_bounds__(512, 2) void scan_kernel(
    const float* __restrict__ keys, const float* __restrict__ Wih,
    const float* __restrict__ Whh, const float* __restrict__ bih,
    const float* __restrict__ bhh, const int* __restrict__ klen,
    const unsigned short* __restrict__ attb, float* __restrict__ out)
{
  const int r0 = blockIdx.x * 16;
  const int tid = threadIdx.x;
  const int lane = tid & 63, wv = tid >> 6;

  __shared__ __align__(16) unsigned short hbf[2][16][136];
  __shared__ __align__(16) unsigned short kbf[2][16][136];
  __shared__ __align__(16) float att_s[T_SEQ][16];
  __shared__ int len_s[16];

  if (tid < 16) len_s[tid] = klen[r0 + tid];
  for (int i = tid; i < 16 * 136; i += 512) ((unsigned short*)hbf[0])[i] = 0;
  // att staged from transposed attb[t][b]: consecutive lanes -> consecutive b
  for (int i = tid; i < T_SEQ * 16; i += 512) {
    int t = i >> 4, m = i & 15;
    att_s[t][m] = bf2f(attb[(size_t)t * B_N + r0 + m]);
  }
  const int pm = tid >> 5, pj = (tid & 31) * 4;
  const float* kbase = keys + ((size_t)(r0 + pm) * T_SEQ) * H_DIM + pj;
  {  // k_0 -> kbf[0], k_1 -> kbf[1]
    float4 k0 = *(const float4*)kbase;
    float4 k1 = *(const float4*)(kbase + H_DIM);
    uint2 p0; p0.x = pack2bf(k0.x, k0.y); p0.y = pack2bf(k0.z, k0.w);
    uint2 p1; p1.x = pack2bf(k1.x, k1.y); p1.y = pack2bf(k1.z, k1.w);
    *(uint2*)&kbf[0][pm][pj] = p0;
    *(uint2*)&kbf[1][pm][pj] = p1;
  }
  float4 kvA = *(const float4*)(kbase + 2 * H_DIM);  // k_2 (T>=3 always)
  float4 kvB;

  // weight fragments (B): lane holds W[g*128+ocol][k-slice]
  short8 whf[3][4], wif[3][4];
  const int ocol = wv * 16 + (lane & 15);
  const int kb = (lane >> 4) * 8;
#pragma unroll
  for (int g = 0; g < 3; ++g) {
    int row = g * 128 + ocol;
#pragma unroll
    for (int kc = 0; kc < 4; ++kc) {
      int kk = kc * 32 + kb;
      whf[g][kc] = pack8(Whh + (size_t)row * H_DIM + kk);
      wif[g][kc] = pack8(Wih + (size_t)row * H_DIM + kk);
    }
  }
  const float br_  = bih[ocol] + bhh[ocol];
  const float bz_  = bih[128 + ocol] + bhh[128 + ocol];
  const float bin_ = bih[256 + ocol];
  const float bhn_ = bhh[256 + ocol];

  int tmax = 0;
#pragma unroll
  for (int m = 0; m < 16; ++m) tmax = max(tmax, len_s[m]);
  const int mrow0 = (lane >> 4) * 4;
  int lenr[4];
  float hreg[4];
#pragma unroll
  for (int r = 0; r < 4; ++r) { lenr[r] = len_s[mrow0 + r]; hreg[r] = 0.0f; }
  const int arow = lane & 15;

  __syncthreads();   // staging visible
  short8 akA[4], akB[4];
  akA[0] = *(const short8*)&kbf[0][arow][kb];        // prefetch k_0 frags
  akA[1] = *(const short8*)&kbf[0][arow][32 + kb];
  akA[2] = *(const short8*)&kbf[0][arow][64 + kb];
  akA[3] = *(const short8*)&kbf[0][arow][96 + kb];
  __syncthreads();   // all waves' k_0 reads done before STEP(0) overwrites kbf[0]

// Per step t (BUF=t&1, NB=BUF^1):
//   AKC holds k_t (prefetched last step); AKN <- kbf[NB] = k_{t+1} frags.
//   KVC holds k_{t+2} (global-loaded last step) -> staged into kbf[BUF];
//   KVN <- global k_{t+3}.  h read from hbf[BUF], written to hbf[NB].
#define SCAN_STEP(BUF, NB, AKC, AKN, KVC, KVN, TT)                              \
  do {                                                                          \
    short8 ah0 = *(const short8*)&hbf[BUF][arow][kb];                           \
    short8 ah1 = *(const short8*)&hbf[BUF][arow][32 + kb];                      \
    short8 ah2 = *(const short8*)&hbf[BUF][arow][64 + kb];                      \
    short8 ah3 = *(const short8*)&hbf[BUF][arow][96 + kb];                      \
    floatx4 att4 = *(const floatx4*)&att_s[TT][mrow0];                          \
    int tf = (TT) + 3; if (tf > T_SEQ - 1) tf = T_SEQ - 1;                      \
    KVN = *(const float4*)(kbase + (size_t)tf * H_DIM);                         \
    /* k-side MFMAs: operands already in regs, zero LDS wait */                 \
    floatx4 ark = {0.f, 0.f, 0.f, 0.f};                                         \
    floatx4 azk = {0.f, 0.f, 0.f, 0.f};                                         \
    floatx4 ain = {bin_, bin_, bin_, bin_};                                     \
    ark = mfma16(AKC[0], wif[0][0], ark); ark = mfma16(AKC[1], wif[0][1], ark); \
    ark = mfma16(AKC[2], wif[0][2], ark); ark = mfma16(AKC[3], wif[0][3], ark); \
    azk = mfma16(AKC[0], wif[1][0], azk); azk = mfma16(AKC[1], wif[1][1], azk); \
    azk = mfma16(AKC[2], wif[1][2], azk); azk = mfma16(AKC[3], wif[1][3], azk); \
    ain = mfma16(AKC[0], wif[2][0], ain); ain = mfma16(AKC[1], wif[2][1], ain); \
    ain = mfma16(AKC[2], wif[2][2], ain); ain = mfma16(AKC[3], wif[2][3], ain); \
    /* prefetch next step's k frags (kbf[NB] holds k_{TT+1}, barrier-safe) */   \
    AKN[0] = *(const short8*)&kbf[NB][arow][kb];                                \
    AKN[1] = *(const short8*)&kbf[NB][arow][32 + kb];                           \
    AKN[2] = *(const short8*)&kbf[NB][arow][64 + kb];                           \
    AKN[3] = *(const short8*)&kbf[NB][arow][96 + kb];                           \
    {  /* stage k_{TT+2} into kbf[BUF] (k_TT there fully consumed last step) */ \
      uint2 p; p.x = pack2bf(KVC.x, KVC.y); p.y = pack2bf(KVC.z, KVC.w);        \
      *(uint2*)&kbf[BUF][pm][pj] = p;                                           \
    }                                                                           \
    /* h-side MFMAs (compiler inserts lgkm waits for ah reads) */               \
    floatx4 arh = {br_, br_, br_, br_};                                         \
    floatx4 azh = {bz_, bz_, bz_, bz_};                                         \
    floatx4 ahn = {bhn_, bhn_, bhn_, bhn_};                                     \
    arh = mfma16(ah0, whf[0][0], arh); arh = mfma16(ah1, whf[0][1], arh);       \
    arh = mfma16(ah2, whf[0][2], arh); arh = mfma16(ah3, whf[0][3], arh);       \
    azh = mfma16(ah0, whf[1][0], azh); azh = mfma16(ah1, whf[1][1], azh);       \
    azh = mfma16(ah2, whf[1][2], azh); azh = mfma16(ah3, whf[1][3], azh);       \
    ahn = mfma16(ah0, whf[2][0], ahn); ahn = mfma16(ah1, whf[2][1], ahn);       \
    ahn = mfma16(ah2, whf[2][2], ahn); ahn = mfma16(ah3, whf[2][3], ahn);       \
    _Pragma("unroll")                                                           \
    for (int r = 0; r < 4; ++r) {                                               \
      float rr = fsig(arh[r] + ark[r]);                                         \
      float zz = fsig(azh[r] + azk[r]);                                         \
      float nn = ftanh(ain[r] + rr * ahn[r]);                                   \
      float z2 = att4[r] * zz;                                                  \
      float hn = fmaf(z2, nn - hreg[r], hreg[r]);                               \
      hreg[r] = ((TT) < lenr[r]) ? hn : hreg[r];                                \
      hbf[NB][mrow0 + r][ocol] = f2bf(hreg[r]);                                 \
    }                                                                           \
    /* lgkm-only barrier: global k prefetch stays in flight across it */        \
    __asm__ volatile("s_waitcnt lgkmcnt(0)\n\ts_barrier" ::: "memory");         \
  } while (0)

  int t = 0;
  for (; t + 1 < tmax; t += 2) {
    SCAN_STEP(0, 1, akA, akB, kvA, kvB, t);
    SCAN_STEP(1, 0, akB, akA, kvB, kvA, t + 1);
  }
  if (t < tmax) SCAN_STEP(0, 1, akA, akB, kvA, kvB, t);
#undef SCAN_STEP

#pragma unroll
  for (int r = 0; r < 4; ++r)
    out[(size_t)(r0 + mrow0 + r) * H_DIM + ocol] = hreg[r];
}

extern "C" void kernel_launch(void* const* d_in, const int* in_sizes, int n_in,
                              void* d_out, int out_size, void* d_ws, size_t ws_size,
                              hipStream_t stream) {
  const float* query = (const float*)d_in[0];
  const float* keys  = (const float*)d_in[1];
  const float* W0    = (const float*)d_in[2];
  const float* b0    = (const float*)d_in[3];
  const float* W1    = (const float*)d_in[4];
  const float* b1    = (const float*)d_in[5];
  const float* Wd    = (const float*)d_in[6];
  const float* bd    = (const float*)d_in[7];
  const float* Wih   = (const float*)d_in[8];
  const float* Whh   = (const float*)d_in[9];
  const float* bih   = (const float*)d_in[10];
  const float* bhh   = (const float*)d_in[11];
  const int*   klen  = (const int*)d_in[12];

  char* ws = (char*)d_ws;
  unsigned short* att_bf = (unsigned short*)(ws + OFF_ATT);
  float*  c_ws  = (float*)(ws + OFF_C);
  float*  u1_ws = (float*)(ws + OFF_U1);
  short8* fr_ws = (short8*)(ws + OFF_FR);
  short8* w1f_ws = (short8*)(ws + OFF_W1F);
  float* out = (float*)d_out;

  hipLaunchKernelGGL(prep_kernel, dim3(8), dim3(256), 0, stream, W0, W1, u1_ws, fr_ws, w1f_ws);
  hipLaunchKernelGGL(c_kernel, dim3(B_N / 16), dim3(256), 0, stream, query, u1_ws, b0, c_ws);
  hipLaunchKernelGGL(att_kernel, dim3(4, B_N), dim3(256), 0, stream,
                     query, keys, c_ws, fr_ws, w1f_ws, b1, Wd, bd, klen, att_bf);
  hipLaunchKernelGGL(scan_kernel, dim3(B_N / 16), dim3(512), 0, stream,
                     keys, Wih, Whh, bih, bhh, klen, att_bf, out);
}

// Round 2
// 477.410 us; speedup vs baseline: 1.3189x; 1.1035x over previous
//
#include <hip/hip_runtime.h>
#include <stdint.h>
#include <stddef.h>

#define B_N   2048
#define T_SEQ 200
#define H_DIM 128

typedef __attribute__((ext_vector_type(8))) short short8;
typedef __attribute__((ext_vector_type(4))) float floatx4;

// ws layout (bytes) — total 1,411,072 <= 1,638,400 proven safe in R1
#define OFF_ATT 0u         // ushort[B][T]        819200  ([b][t]: att writes coalesced)
#define OFF_C   819200u    // float [B][64]       524288
#define OFF_U1  1343488u   // float [128][64]      32768
#define OFF_FR  1376256u   // short8[4][8][64]     32768
#define OFF_W1F 1409024u   // short8[2][64]         2048

__device__ __forceinline__ unsigned rnd_bf(float f) {
  union { float f; unsigned u; } v; v.f = f;
  return v.u + 0x7FFFu + ((v.u >> 16) & 1u);
}
__device__ __forceinline__ unsigned short f2bf(float f) {
  return (unsigned short)(rnd_bf(f) >> 16);
}
// pack two floats -> dword of 2 bf16 (lo in low16) via v_perm_b32
__device__ __forceinline__ unsigned pack2bf(float lo, float hi) {
  return __builtin_amdgcn_perm(rnd_bf(hi), rnd_bf(lo), 0x07060302u);
}
__device__ __forceinline__ float bf2f(unsigned short u) {
  union { unsigned u; float f; } v; v.u = ((unsigned)u) << 16; return v.f;
}

#define LOG2E 1.4426950408889634f
// att kernel still uses the generic forms (cost there is negligible)
__device__ __forceinline__ float fsig(float x) {
  return __builtin_amdgcn_rcpf(1.0f + __builtin_amdgcn_exp2f(-LOG2E * x));
}

__device__ __forceinline__ floatx4 mfma16(short8 a, short8 b, floatx4 c) {
  return __builtin_amdgcn_mfma_f32_16x16x32_bf16(a, b, c, 0, 0, 0);
}
// pack 8 floats (scaled by s) to bf16 fragment
__device__ __forceinline__ short8 pack8s(const float* p, float s) {
  short8 r;
#pragma unroll
  for (int j = 0; j < 8; ++j) r[j] = (short)f2bf(p[j] * s);
  return r;
}

// ---------------------------------------------------------------------------
// prep: fold W0 into u1 (fp32, for c-GEMM) and bf16 MFMA B-fragments for
// layer0 (u2|u3) and layer1 (W1^T). Grid-strided over 8 blocks.
// ---------------------------------------------------------------------------
__global__ __launch_bounds__(256) void prep_kernel(
    const float* __restrict__ W0, const float* __restrict__ W1,
    float* __restrict__ u1_ws, short8* __restrict__ fr_ws,
    short8* __restrict__ w1f_ws)
{
  const int gid = blockIdx.x * 256 + threadIdx.x;
  const int gs  = gridDim.x * 256;
  for (int i = gid; i < 128 * 64; i += gs) {
    int k = i >> 6, o = i & 63;
    u1_ws[i] = W0[o * 512 + k] + W0[o * 512 + 256 + k];
  }
  for (int f = gid; f < 4 * 8 * 64; f += gs) {
    int ln = f & 63, kc = (f >> 6) & 7, tt = f >> 9;
    int o = tt * 16 + (ln & 15);
    int k0 = kc * 32 + ((ln >> 4) * 8);
    short8 v;
#pragma unroll
    for (int j = 0; j < 8; ++j) {
      int ks = k0 + j;
      float x = (ks < 128) ? (W0[o * 512 + 128 + ks] - W0[o * 512 + 256 + ks])
                           : W0[o * 512 + 384 + (ks - 128)];
      v[j] = (short)f2bf(x);
    }
    fr_ws[f] = v;
  }
  for (int f = gid; f < 2 * 64; f += gs) {
    int ln = f & 63, kc = f >> 6;
    int n = ln & 15, k0 = kc * 32 + ((ln >> 4) * 8);
    short8 v;
#pragma unroll
    for (int j = 0; j < 8; ++j) v[j] = (short)f2bf(W1[n * 64 + k0 + j]);
    w1f_ws[f] = v;
  }
}

// ---------------------------------------------------------------------------
// c_kernel: c[b][o] = b0[o] + sum_k q[b][k] * u1[k][o].  16 b per block.
// ---------------------------------------------------------------------------
__global__ __launch_bounds__(256) void c_kernel(
    const float* __restrict__ query, const float* __restrict__ u1_ws,
    const float* __restrict__ b0, float* __restrict__ c_ws)
{
  const int blk = blockIdx.x, tid = threadIdx.x;
  __shared__ float qs[16 * 128];
  for (int i = tid; i < 512; i += 256)
    *(float4*)&qs[i * 4] = *(const float4*)(query + (size_t)blk * 2048 + i * 4);
  __syncthreads();
  const int o = tid & 63, bb = tid >> 6;
  float a0 = b0[o], a1 = a0, a2 = a0, a3 = a0;
  const float* qr = qs + bb * 512;
#pragma unroll 4
  for (int k = 0; k < 128; ++k) {
    float w = u1_ws[k * 64 + o];
    a0 = fmaf(qr[k], w, a0);
    a1 = fmaf(qr[128 + k], w, a1);
    a2 = fmaf(qr[256 + k], w, a2);
    a3 = fmaf(qr[384 + k], w, a3);
  }
  const int b = blk * 16 + bb * 4;
  c_ws[(b + 0) * 64 + o] = a0;
  c_ws[(b + 1) * 64 + o] = a1;
  c_ws[(b + 2) * 64 + o] = a2;
  c_ws[(b + 3) * 64 + o] = a3;
}

// ---------------------------------------------------------------------------
// att v2: ONE block per b (grid 2048). Fragments/q/c loaded once; loop over
// t-tiles with early termination at len (avg ~2.1 of 4 tiles). Scores written
// [b][t]: one coalesced 128B store per tile. Zero-fill of the tail is a
// contiguous strided store.
// ---------------------------------------------------------------------------
__global__ __launch_bounds__(256) void att_kernel(
    const float* __restrict__ query, const float* __restrict__ keys,
    const float* __restrict__ c_ws, const short8* __restrict__ fr_ws,
    const short8* __restrict__ w1f_ws, const float* __restrict__ b1,
    const float* __restrict__ Wd, const float* __restrict__ bd,
    const int* __restrict__ klen, unsigned short* __restrict__ attb)
{
  const int b   = blockIdx.x;
  const int tid = threadIdx.x;
  const int lane = tid & 63, wv = tid >> 6;
  const int kb = (lane >> 4) * 8;

  __shared__ float qs[H_DIM];
  __shared__ __align__(16) unsigned short A[64][264];  // [t][k] bf16, K=256
  __shared__ __align__(16) unsigned short a0b[64][72]; // layer0 activations bf16
  __shared__ float a1s[64][20];

  const int len = klen[b];

  if (tid < H_DIM) qs[tid] = query[(size_t)b * H_DIM + tid];

  // B-fragments for this wave's o-tile (prebuilt in ws) — loaded ONCE per b
  short8 bf[8];
  {
    const short8* frp = fr_ws + (size_t)wv * 8 * 64;
#pragma unroll
    for (int kc = 0; kc < 8; ++kc) bf[kc] = frp[kc * 64 + lane];
  }
  short8 w1f0 = w1f_ws[lane], w1f1 = w1f_ws[64 + lane];
  const float b1v = b1[lane & 15];
  const float co = c_ws[(size_t)b * 64 + wv * 16 + (lane & 15)];
  const float bd0 = bd[0];
  float wd_r[16];
#pragma unroll
  for (int i = 0; i < 16; ++i) wd_r[i] = Wd[i];
  __syncthreads();

  int t0 = 0;
  for (; t0 < len; t0 += 64) {
    {  // stage A = [k | q*k] bf16 for rows t0..t0+63
      int tl = tid >> 2, q4 = tid & 3;
      int tg = t0 + tl;
      bool v = (tg < T_SEQ);
      const float* krow = keys + ((size_t)b * T_SEQ + (v ? tg : 0)) * H_DIM + q4 * 32;
#pragma unroll
      for (int i = 0; i < 32; i += 4) {
        float4 kv = v ? *(const float4*)(krow + i) : make_float4(0.f, 0.f, 0.f, 0.f);
        int col = q4 * 32 + i;
        *(unsigned*)&A[tl][col]     = pack2bf(kv.x, kv.y);
        *(unsigned*)&A[tl][col + 2] = pack2bf(kv.z, kv.w);
        *(unsigned*)&A[tl][128 + col]     = pack2bf(kv.x * qs[col + 0], kv.y * qs[col + 1]);
        *(unsigned*)&A[tl][128 + col + 2] = pack2bf(kv.z * qs[col + 2], kv.w * qs[col + 3]);
      }
    }
    __syncthreads();

    // layer0 MFMA
#pragma unroll
    for (int tt = 0; tt < 4; ++tt) {
      floatx4 acc = {co, co, co, co};
      int row = tt * 16 + (lane & 15);
#pragma unroll
      for (int kc = 0; kc < 8; ++kc)
        acc = mfma16(*(const short8*)&A[row][kc * 32 + kb], bf[kc], acc);
#pragma unroll
      for (int r = 0; r < 4; ++r)
        a0b[tt * 16 + (lane >> 4) * 4 + r][wv * 16 + (lane & 15)] = f2bf(fsig(acc[r]));
    }
    __syncthreads();

    // layer1 MFMA: wave wv owns t-rows wv*16..+15, 16 outputs
    {
      floatx4 acc1 = {b1v, b1v, b1v, b1v};
      int r2 = wv * 16 + (lane & 15);
      acc1 = mfma16(*(const short8*)&a0b[r2][kb],      w1f0, acc1);
      acc1 = mfma16(*(const short8*)&a0b[r2][32 + kb], w1f1, acc1);
#pragma unroll
      for (int r = 0; r < 4; ++r)
        a1s[wv * 16 + (lane >> 4) * 4 + r][lane & 15] = fsig(acc1[r]);
    }
    __syncthreads();

    if (tid < 64) {
      int tg = t0 + tid;
      if (tg < T_SEQ) {
        float s = bd0;
#pragma unroll
        for (int i = 0; i < 16; ++i) s += a1s[tid][i] * wd_r[i];
        attb[(size_t)b * T_SEQ + tg] = (tg < len) ? f2bf(s) : (unsigned short)0;
      }
    }
    __syncthreads();  // a1s/A reuse next tile
  }
  // zero tail [t0, T)
  for (int i = t0 + tid; i < T_SEQ; i += 256) attb[(size_t)b * T_SEQ + i] = 0;
}

// ---------------------------------------------------------------------------
// AUGRU scan v3: v2 structure +
//  - log2e folded into weight fragments/biases at pack time (r/z: -log2e,
//    n-gate both sides: -2*log2e) -> sigmoid/tanh lose their multiply.
//  - per-row length mask DROPPED: att scores are exactly 0 for t>=len, so
//    h = fma(att*z, n-h, h) reproduces h bit-exactly (n always finite).
//  - att staged from [b][t] layout via dword loads (contiguous 400B runs).
// ---------------------------------------------------------------------------
__global__ __launch_bounds__(512, 2) void scan_kernel(
    const float* __restrict__ keys, const float* __restrict__ Wih,
    const float* __restrict__ Whh, const float* __restrict__ bih,
    const float* __restrict__ bhh, const int* __restrict__ klen,
    const unsigned short* __restrict__ attb, float* __restrict__ out)
{
  const int r0 = blockIdx.x * 16;
  const int tid = threadIdx.x;
  const int lane = tid & 63, wv = tid >> 6;

  __shared__ __align__(16) unsigned short hbf[2][16][136];
  __shared__ __align__(16) unsigned short kbf[2][16][136];
  __shared__ __align__(16) float att_s[T_SEQ][16];
  __shared__ int len_s[16];

  if (tid < 16) len_s[tid] = klen[r0 + tid];
  for (int i = tid; i < 16 * 136; i += 512) ((unsigned short*)hbf[0])[i] = 0;
  // att staged from [b][t] layout: dword loads, 400B contiguous per row
  {
    const unsigned* attw = (const unsigned*)attb;  // [b][100] dwords
    for (int i = tid; i < 16 * 100; i += 512) {
      int m = i / 100, t2 = i - m * 100;
      unsigned w = attw[(size_t)(r0 + m) * 100 + t2];
      att_s[2 * t2][m]     = bf2f((unsigned short)(w & 0xFFFFu));
      att_s[2 * t2 + 1][m] = bf2f((unsigned short)(w >> 16));
    }
  }
  const int pm = tid >> 5, pj = (tid & 31) * 4;
  const float* kbase = keys + ((size_t)(r0 + pm) * T_SEQ) * H_DIM + pj;
  {  // k_0 -> kbf[0], k_1 -> kbf[1]
    float4 k0 = *(const float4*)kbase;
    float4 k1 = *(const float4*)(kbase + H_DIM);
    uint2 p0; p0.x = pack2bf(k0.x, k0.y); p0.y = pack2bf(k0.z, k0.w);
    uint2 p1; p1.x = pack2bf(k1.x, k1.y); p1.y = pack2bf(k1.z, k1.w);
    *(uint2*)&kbf[0][pm][pj] = p0;
    *(uint2*)&kbf[1][pm][pj] = p1;
  }
  float4 kvA = *(const float4*)(kbase + 2 * H_DIM);  // k_2 (T>=3 always)
  float4 kvB;

  // weight fragments (B), pre-scaled: r/z rows by -log2e, n rows by -2log2e
  short8 whf[3][4], wif[3][4];
  const int ocol = wv * 16 + (lane & 15);
  const int kb = (lane >> 4) * 8;
#pragma unroll
  for (int g = 0; g < 3; ++g) {
    const float sc = (g == 2) ? (-2.0f * LOG2E) : (-LOG2E);
    int row = g * 128 + ocol;
#pragma unroll
    for (int kc = 0; kc < 4; ++kc) {
      int kk = kc * 32 + kb;
      whf[g][kc] = pack8s(Whh + (size_t)row * H_DIM + kk, sc);
      wif[g][kc] = pack8s(Wih + (size_t)row * H_DIM + kk, sc);
    }
  }
  const float br_  = -LOG2E * (bih[ocol] + bhh[ocol]);
  const float bz_  = -LOG2E * (bih[128 + ocol] + bhh[128 + ocol]);
  const float bin_ = -2.0f * LOG2E * bih[256 + ocol];
  const float bhn_ = -2.0f * LOG2E * bhh[256 + ocol];

  int tmax = 0;
#pragma unroll
  for (int m = 0; m < 16; ++m) tmax = max(tmax, len_s[m]);
  const int mrow0 = (lane >> 4) * 4;
  float hreg[4];
#pragma unroll
  for (int r = 0; r < 4; ++r) hreg[r] = 0.0f;
  const int arow = lane & 15;

  __syncthreads();   // staging visible
  short8 akA[4], akB[4];
  akA[0] = *(const short8*)&kbf[0][arow][kb];        // prefetch k_0 frags
  akA[1] = *(const short8*)&kbf[0][arow][32 + kb];
  akA[2] = *(const short8*)&kbf[0][arow][64 + kb];
  akA[3] = *(const short8*)&kbf[0][arow][96 + kb];
  __syncthreads();   // all waves' k_0 reads done before STEP(0) overwrites kbf[0]

// Per step t (BUF=t&1, NB=BUF^1):
//   AKC holds k_t (prefetched last step); AKN <- kbf[NB] = k_{t+1} frags.
//   KVC holds k_{t+2} (global-loaded last step) -> staged into kbf[BUF];
//   KVN <- global k_{t+3}.  h read from hbf[BUF], written to hbf[NB].
// Preactivations arrive PRE-SCALED: s_r/s_z = -log2e*(...), s_n = -2log2e*(...)
//   r = rcp(1+exp2(s_r)); n = 2*rcp(1+exp2(s_n)) - 1.
#define SCAN_STEP(BUF, NB, AKC, AKN, KVC, KVN, TT)                              \
  do {                                                                          \
    short8 ah0 = *(const short8*)&hbf[BUF][arow][kb];                           \
    short8 ah1 = *(const short8*)&hbf[BUF][arow][32 + kb];                      \
    short8 ah2 = *(const short8*)&hbf[BUF][arow][64 + kb];                      \
    short8 ah3 = *(const short8*)&hbf[BUF][arow][96 + kb];                      \
    floatx4 att4 = *(const floatx4*)&att_s[TT][mrow0];                          \
    int tf = (TT) + 3; if (tf > T_SEQ - 1) tf = T_SEQ - 1;                      \
    KVN = *(const float4*)(kbase + (size_t)tf * H_DIM);                         \
    /* k-side MFMAs: operands already in regs, zero LDS wait */                 \
    floatx4 ark = {0.f, 0.f, 0.f, 0.f};                                         \
    floatx4 azk = {0.f, 0.f, 0.f, 0.f};                                         \
    floatx4 ain = {bin_, bin_, bin_, bin_};                                     \
    ark = mfma16(AKC[0], wif[0][0], ark); ark = mfma16(AKC[1], wif[0][1], ark); \
    ark = mfma16(AKC[2], wif[0][2], ark); ark = mfma16(AKC[3], wif[0][3], ark); \
    azk = mfma16(AKC[0], wif[1][0], azk); azk = mfma16(AKC[1], wif[1][1], azk); \
    azk = mfma16(AKC[2], wif[1][2], azk); azk = mfma16(AKC[3], wif[1][3], azk); \
    ain = mfma16(AKC[0], wif[2][0], ain); ain = mfma16(AKC[1], wif[2][1], ain); \
    ain = mfma16(AKC[2], wif[2][2], ain); ain = mfma16(AKC[3], wif[2][3], ain); \
    /* prefetch next step's k frags (kbf[NB] holds k_{TT+1}, barrier-safe) */   \
    AKN[0] = *(const short8*)&kbf[NB][arow][kb];                                \
    AKN[1] = *(const short8*)&kbf[NB][arow][32 + kb];                           \
    AKN[2] = *(const short8*)&kbf[NB][arow][64 + kb];                           \
    AKN[3] = *(const short8*)&kbf[NB][arow][96 + kb];                           \
    {  /* stage k_{TT+2} into kbf[BUF] (k_TT there fully consumed last step) */ \
      uint2 p; p.x = pack2bf(KVC.x, KVC.y); p.y = pack2bf(KVC.z, KVC.w);        \
      *(uint2*)&kbf[BUF][pm][pj] = p;                                           \
    }                                                                           \
    /* h-side MFMAs (compiler inserts lgkm waits for ah reads) */               \
    floatx4 arh = {br_, br_, br_, br_};                                         \
    floatx4 azh = {bz_, bz_, bz_, bz_};                                         \
    floatx4 ahn = {bhn_, bhn_, bhn_, bhn_};                                     \
    arh = mfma16(ah0, whf[0][0], arh); arh = mfma16(ah1, whf[0][1], arh);       \
    arh = mfma16(ah2, whf[0][2], arh); arh = mfma16(ah3, whf[0][3], arh);       \
    azh = mfma16(ah0, whf[1][0], azh); azh = mfma16(ah1, whf[1][1], azh);       \
    azh = mfma16(ah2, whf[1][2], azh); azh = mfma16(ah3, whf[1][3], azh);       \
    ahn = mfma16(ah0, whf[2][0], ahn); ahn = mfma16(ah1, whf[2][1], ahn);       \
    ahn = mfma16(ah2, whf[2][2], ahn); ahn = mfma16(ah3, whf[2][3], ahn);       \
    _Pragma("unroll")                                                           \
    for (int r = 0; r < 4; ++r) {                                               \
      float rr = __builtin_amdgcn_rcpf(1.0f + __builtin_amdgcn_exp2f(arh[r] + ark[r])); \
      float zz = __builtin_amdgcn_rcpf(1.0f + __builtin_amdgcn_exp2f(azh[r] + azk[r])); \
      float sn = fmaf(rr, ahn[r], ain[r]);                                      \
      float nn = fmaf(2.0f, __builtin_amdgcn_rcpf(1.0f + __builtin_amdgcn_exp2f(sn)), -1.0f); \
      float z2 = att4[r] * zz;                                                  \
      hreg[r] = fmaf(z2, nn - hreg[r], hreg[r]);                                \
      hbf[NB][mrow0 + r][ocol] = f2bf(hreg[r]);                                 \
    }                                                                           \
    /* lgkm-only barrier: global k prefetch stays in flight across it */        \
    __asm__ volatile("s_waitcnt lgkmcnt(0)\n\ts_barrier" ::: "memory");         \
  } while (0)

  int t = 0;
  for (; t + 1 < tmax; t += 2) {
    SCAN_STEP(0, 1, akA, akB, kvA, kvB, t);
    SCAN_STEP(1, 0, akB, akA, kvB, kvA, t + 1);
  }
  if (t < tmax) SCAN_STEP(0, 1, akA, akB, kvA, kvB, t);
#undef SCAN_STEP

#pragma unroll
  for (int r = 0; r < 4; ++r)
    out[(size_t)(r0 + mrow0 + r) * H_DIM + ocol] = hreg[r];
}

extern "C" void kernel_launch(void* const* d_in, const int* in_sizes, int n_in,
                              void* d_out, int out_size, void* d_ws, size_t ws_size,
                              hipStream_t stream) {
  const float* query = (const float*)d_in[0];
  const float* keys  = (const float*)d_in[1];
  const float* W0    = (const float*)d_in[2];
  const float* b0    = (const float*)d_in[3];
  const float* W1    = (const float*)d_in[4];
  const float* b1    = (const float*)d_in[5];
  const float* Wd    = (const float*)d_in[6];
  const float* bd    = (const float*)d_in[7];
  const float* Wih   = (const float*)d_in[8];
  const float* Whh   = (const float*)d_in[9];
  const float* bih   = (const float*)d_in[10];
  const float* bhh   = (const float*)d_in[11];
  const int*   klen  = (const int*)d_in[12];

  char* ws = (char*)d_ws;
  unsigned short* att_bf = (unsigned short*)(ws + OFF_ATT);
  float*  c_ws  = (float*)(ws + OFF_C);
  float*  u1_ws = (float*)(ws + OFF_U1);
  short8* fr_ws = (short8*)(ws + OFF_FR);
  short8* w1f_ws = (short8*)(ws + OFF_W1F);
  float* out = (float*)d_out;

  hipLaunchKernelGGL(prep_kernel, dim3(8), dim3(256), 0, stream, W0, W1, u1_ws, fr_ws, w1f_ws);
  hipLaunchKernelGGL(c_kernel, dim3(B_N / 16), dim3(256), 0, stream, query, u1_ws, b0, c_ws);
  hipLaunchKernelGGL(att_kernel, dim3(B_N), dim3(256), 0, stream,
                     query, keys, c_ws, fr_ws, w1f_ws, b1, Wd, bd, klen, att_bf);
  hipLaunchKernelGGL(scan_kernel, dim3(B_N / 16), dim3(512), 0, stream,
                     keys, Wih, Whh, bih, bhh, klen, att_bf, out);
}